// Round 8
// baseline (208.869 us; speedup 1.0000x reference)
//
#include <hip/hip_runtime.h>
#include <stdint.h>

// CapsuleLayer dynamic routing, MI355X. fp32 in/out.
// B=256, N=10, I=1152, D=16, K(Din)=8, ROUTINGS=3.
// R8: DS-pipe diet. K1 per-n reduce = packed butterfly (15 shfl, not 64),
// canonical LDS slots padded 66 (no 4-way bank alias). o precomputed once
// per round by caps_o (sweep prologue = 1 load). Sweep epilogue packed too.

#define BN 256
#define NN 10
#define II 1152
#define DD 16
#define KK 8
#define NT 18          // K1 i-tiles of 64
#define NCH 9          // sweep chunks of 128 i
#define CHI 128

typedef unsigned short ushort_t;
typedef unsigned int uint_t;

__device__ __forceinline__ float bflo(uint_t u) {
    union { uint_t i; float f; } v; v.i = u << 16; return v.f;
}
__device__ __forceinline__ float bfhi(uint_t u) {
    union { uint_t i; float f; } v; v.i = u & 0xffff0000u; return v.f;
}
__device__ __forceinline__ uint_t f2bf(float f) {  // RTNE bf16
    union { float f; uint_t i; } v; v.f = f;
    uint_t x = v.i;
    return (x + 0x7fffu + ((x >> 16) & 1u)) >> 16;
}

// ---------------- K1 + sweep0 partials --------------------------------------
// block = (i-tile of 64, b-quad). 256 thr = 4 waves.
// lane = il*4+dq: thread owns (i = it*64 + wv*16 + il, d-quad dq), 4 b's.
// Per n: compute s[16]=(bb,dj), store u bf16, packed-butterfly over il
// (15 shfl) -> lane holds value bitrev4(il) -> canonical LDS slot.
// part0[b][it][n*16+d] = sum_{i in tile} u  (fp32 pre-pack; 0.1 applied here).
__global__ __launch_bounds__(256) void caps_uhat_s0(const float* __restrict__ xg,
                                                    const float* __restrict__ wg,
                                                    ushort_t* __restrict__ u,
                                                    float* __restrict__ part0,
                                                    int b0, int c4)
{
    __shared__ float red[NN * 4 * 66];  // [n][wv][slot<64, pad to 66], 10.3 KB
    const int tid = threadIdx.x;
    const int lane = tid & 63, wv = tid >> 6;
    const int dq = lane & 3, il = lane >> 2;
    const int it = blockIdx.x / c4;
    const int bl = (blockIdx.x % c4) * 4;      // chunk-local b base (4 b's)
    const int i = it * 64 + wv * 16 + il;

    // value index this lane holds after the packed butterfly = bitrev4(il)
    const int vidx = ((il & 1) << 3) | ((il & 2) << 1) | ((il & 4) >> 1) | ((il & 8) >> 3);
    const int slot = (vidx >> 2) * 16 + dq * 4 + (vidx & 3);  // bb*16 + d

    float xv[4][8];
#pragma unroll
    for (int bb = 0; bb < 4; ++bb) {
        const float4* xp = (const float4*)(xg + ((size_t)(b0 + bl + bb) * II + i) * KK);
        float4 x0 = xp[0], x1 = xp[1];
        xv[bb][0] = x0.x; xv[bb][1] = x0.y; xv[bb][2] = x0.z; xv[bb][3] = x0.w;
        xv[bb][4] = x1.x; xv[bb][5] = x1.y; xv[bb][6] = x1.z; xv[bb][7] = x1.w;
    }

    for (int n = 0; n < NN; ++n) {
        const float4* wp = (const float4*)(wg + (size_t)(n * II + i) * (DD * KK)) + dq * 8;
        float4 w[8];
#pragma unroll
        for (int j = 0; j < 8; ++j) w[j] = wp[j];

        float s[16];   // [bb*4+dj]
#pragma unroll
        for (int dj = 0; dj < 4; ++dj) {
            float4 wa = w[2 * dj], wb = w[2 * dj + 1];
#pragma unroll
            for (int bb = 0; bb < 4; ++bb) {
                s[bb * 4 + dj] = wa.x * xv[bb][0] + wa.y * xv[bb][1]
                               + wa.z * xv[bb][2] + wa.w * xv[bb][3]
                               + wb.x * xv[bb][4] + wb.y * xv[bb][5]
                               + wb.z * xv[bb][6] + wb.w * xv[bb][7];
            }
        }
        // store u (bf16): wave-contiguous 512 B per (b,n)
#pragma unroll
        for (int bb = 0; bb < 4; ++bb) {
            uint2 q;
            q.x = f2bf(s[bb * 4 + 0]) | (f2bf(s[bb * 4 + 1]) << 16);
            q.y = f2bf(s[bb * 4 + 2]) | (f2bf(s[bb * 4 + 3]) << 16);
            *(uint2*)(u + (((size_t)(bl + bb) * NN + n) * II + i) * DD + dq * 4) = q;
        }
        // packed butterfly over il (bits 2..5): 8+4+2+1 = 15 shfl
#pragma unroll
        for (int r = 0; r < 4; ++r) {
            const int m = 4 << r, half = 8 >> r;
#pragma unroll
            for (int j = 0; j < half; ++j) {
                float send = (lane & m) ? s[j] : s[j + half];
                float recv = __shfl_xor(send, m, 64);
                s[j] = ((lane & m) ? s[j + half] : s[j]) + recv;
            }
        }
        red[(n * 4 + wv) * 66 + slot] = s[0];
    }
    __syncthreads();
    for (int idx = tid; idx < 640; idx += 256) {
        int bb = idx / 160, r2 = idx - bb * 160;   // r2 = n*16+d
        int n = r2 >> 4, d = r2 & 15;
        float v = red[(n * 4 + 0) * 66 + bb * 16 + d]
                + red[(n * 4 + 1) * 66 + bb * 16 + d]
                + red[(n * 4 + 2) * 66 + bb * 16 + d]
                + red[(n * 4 + 3) * 66 + bb * 16 + d];
        part0[((size_t)(b0 + bl + bb) * NT + it) * 160 + r2] = 0.1f * v;
    }
}

// ---------------- caps_o: o[b] (+)= squash(sum_p part[b][p]) ----------------
// grid c blocks x 192 thr. mode 0: o = squash(sum); 1: o += squash(sum).
__global__ __launch_bounds__(192) void caps_o(const float* __restrict__ part,
                                              float* __restrict__ o,
                                              int np, int b0, int mode)
{
    const int b = b0 + blockIdx.x;
    const int t = threadIdx.x;
    if (t < 160) {
        float v = 0.f;
        for (int p = 0; p < np; ++p)
            v += part[((size_t)b * np + p) * 160 + t];
        float sq = v * v;
#pragma unroll
        for (int m = 1; m <= 8; m <<= 1) sq += __shfl_xor(sq, m, 64);
        float val = v * (sqrtf(sq) / (1.0f + sq));   // squash scale
        if (mode) o[(size_t)b * 160 + t] += val;
        else      o[(size_t)b * 160 + t]  = val;
    }
}

// ---------------- sweep r=1,2 ----------------------------------------------
// c = softmax_n(<o,u>), partial s = sum c*u over 128 i -> pout[b][ch][160].
__global__ __launch_bounds__(256) void caps_sweep(const ushort_t* __restrict__ u,
                                                  const float* __restrict__ og,
                                                  float* __restrict__ pout, int b0)
{
    __shared__ float red[4 * 4 * 42];   // [wv][dq][40 pad 42]
    __shared__ float o_s[160];
    const int tid = threadIdx.x, g = tid >> 2, ld = tid & 3;
    const int lane = tid & 63, wv = tid >> 6;
    const int cb = blockIdx.x / NCH, ch = blockIdx.x % NCH;
    const int b = b0 + cb;
    const ushort_t* ub = u + (size_t)cb * (NN * II * DD);

    // issue ALL u loads first
    const int i0 = ch * CHI + g;
    uint2 r0[NN], r1[NN];
#pragma unroll
    for (int n = 0; n < NN; ++n) {
        r0[n] = *(const uint2*)(ub + ((size_t)(n * II + i0)) * DD + ld * 4);
        r1[n] = *(const uint2*)(ub + ((size_t)(n * II + i0 + 64)) * DD + ld * 4);
    }
    if (tid < 160) o_s[tid] = og[(size_t)b * 160 + tid];
    __syncthreads();

    float v[40];   // sp[n][j] at n*4+j
#pragma unroll
    for (int k = 0; k < 40; ++k) v[k] = 0.f;

#pragma unroll
    for (int step = 0; step < 2; ++step) {
        float p[NN];
#pragma unroll
        for (int n = 0; n < NN; ++n) {
            uint2 r = step ? r1[n] : r0[n];
            float4 o4 = *(const float4*)&o_s[(n << 4) + (ld << 2)];  // broadcast
            p[n] = bflo(r.x) * o4.x + bfhi(r.x) * o4.y
                 + bflo(r.y) * o4.z + bfhi(r.y) * o4.w;
        }
        float a[NN];
#pragma unroll
        for (int n = 0; n < NN; ++n) {
            float t2 = p[n] + __shfl_xor(p[n], 1, 64);
            a[n] = t2 + __shfl_xor(t2, 2, 64);
        }
        float m = a[0];
#pragma unroll
        for (int n = 1; n < NN; ++n) m = fmaxf(m, a[n]);
        float c[NN], ssum = 0.f;
#pragma unroll
        for (int n = 0; n < NN; ++n) { c[n] = __expf(a[n] - m); ssum += c[n]; }
        float inv = 1.0f / ssum;
#pragma unroll
        for (int n = 0; n < NN; ++n) {
            uint2 r = step ? r1[n] : r0[n];
            float w = c[n] * inv;
            v[n * 4 + 0] += w * bflo(r.x); v[n * 4 + 1] += w * bfhi(r.x);
            v[n * 4 + 2] += w * bflo(r.y); v[n * 4 + 3] += w * bfhi(r.y);
        }
    }

    // packed butterfly over il (bits 2..5): 20+10+5+(2+1) = 38 shfl
#pragma unroll
    for (int r = 0; r < 3; ++r) {
        const int m = 4 << r, half = 20 >> r;
#pragma unroll
        for (int j = 0; j < half; ++j) {
            float send = (lane & m) ? v[j] : v[j + half];
            float recv = __shfl_xor(send, m, 64);
            v[j] = ((lane & m) ? v[j + half] : v[j]) + recv;
        }
    }
    // m=32, L=5: packed on first 4, plain on the leftover v[4]
#pragma unroll
    for (int j = 0; j < 2; ++j) {
        float send = (lane & 32) ? v[j] : v[j + 2];
        float recv = __shfl_xor(send, 32, 64);
        v[j] = ((lane & 32) ? v[j + 2] : v[j]) + recv;
    }
    v[4] += __shfl_xor(v[4], 32, 64);

    const int base5 = ((lane >> 2) & 1) * 20 + ((lane >> 3) & 1) * 10 + ((lane >> 4) & 1) * 5;
    float* rr = &red[(wv * 4 + ld) * 42];
    const int baseA = base5 + ((lane >> 5) & 1) * 2;
    rr[baseA] = v[0];
    rr[baseA + 1] = v[1];
    if (!(lane & 32)) rr[base5 + 4] = v[4];
    __syncthreads();

    if (tid < 160) {
        int n = tid >> 4, d = tid & 15, dq = d >> 2, j = d & 3;
        float s = red[(0 * 4 + dq) * 42 + n * 4 + j]
                + red[(1 * 4 + dq) * 42 + n * 4 + j]
                + red[(2 * 4 + dq) * 42 + n * 4 + j]
                + red[(3 * 4 + dq) * 42 + n * 4 + j];
        pout[((size_t)b * NCH + ch) * 160 + tid] = s;
    }
}

extern "C" void kernel_launch(void* const* d_in, const int* in_sizes, int n_in,
                              void* d_out, int out_size, void* d_ws, size_t ws_size,
                              hipStream_t stream)
{
    const float* xg = (const float*)d_in[0];  // [B,I,K]
    const float* wg = (const float*)d_in[1];  // [N,I,D,K]
    if (n_in >= 2 && in_sizes[0] == NN * II * DD * KK) {
        const float* t = xg; xg = wg; wg = t;
    }
    float* outp = (float*)d_out;

    const size_t perB = (size_t)NN * II * DD * 2;        // 368,640 B bf16 u per b
    const size_t p0B  = (size_t)BN * NT * 160 * 4;       // 2,949,120
    const size_t p12B = (size_t)BN * NCH * 160 * 4;      // 1,474,560 each
    const size_t oB   = (size_t)BN * 160 * 4;            // 163,840
    size_t extra = p0B + 2 * p12B + oB;
    size_t avail = (ws_size > extra) ? ws_size - extra : 0;
    int C = 256;
    if (avail < (size_t)256 * perB) {
        C = (int)(avail / perB);
        C &= ~15;
        if (C < 16) C = 16;
    }
    ushort_t* uws = (ushort_t*)d_ws;
    float* part0 = (float*)((char*)d_ws + (size_t)C * perB);
    float* part1 = part0 + (size_t)BN * NT * 160;
    float* part2 = part1 + (size_t)BN * NCH * 160;
    float* ovec  = part2 + (size_t)BN * NCH * 160;

    for (int b0 = 0; b0 < BN; b0 += C) {
        int c = (BN - b0 < C) ? (BN - b0) : C;
        int c4 = c / 4;
        caps_uhat_s0<<<NT * c4, 256, 0, stream>>>(xg, wg, uws, part0, b0, c4);
        caps_o      <<<c,       192, 0, stream>>>(part0, ovec, NT, b0, 0);
        caps_sweep  <<<c * NCH, 256, 0, stream>>>(uws, ovec, part1, b0);
        caps_o      <<<c,       192, 0, stream>>>(part1, ovec, NCH, b0, 1);
        caps_sweep  <<<c * NCH, 256, 0, stream>>>(uws, ovec, part2, b0);
        caps_o      <<<c,       192, 0, stream>>>(part2, outp, NCH, b0, 0);
    }
}